// Round 1
// baseline (2401.086 us; speedup 1.0000x reference)
//
#include <hip/hip_runtime.h>
#include <stdint.h>

#define NN 20000
#define NE 32000
#define BN_EPS 1e-5f

typedef __attribute__((ext_vector_type(8))) __bf16 bf16x8;
typedef __attribute__((ext_vector_type(4))) float f32x4;
typedef unsigned short u16;
typedef uint32_t u32;

__device__ __forceinline__ u16 f2bf(float f) {
    u32 u = __float_as_uint(f);
    u += 0x7FFFu + ((u >> 16) & 1u);
    return (u16)(u >> 16);
}
__device__ __forceinline__ float bf2f(u16 u) {
    return __uint_as_float(((u32)u) << 16);
}

__device__ __forceinline__ void gload_lds16(const void* g, void* l) {
    __builtin_amdgcn_global_load_lds(
        (const __attribute__((address_space(1))) void*)g,
        (__attribute__((address_space(3))) void*)(uintptr_t)l,
        16, 0, 0);
}

// ---------------- GEMM: C[M][N](bf16) = A[M][K](bf16) * B^T  (B stored [N][K] bf16)
// EPI 0: raw bf16 store; EPI 1: bias + relu -> bf16
template <int EPI>
__global__ __launch_bounds__(256, 2) void gemm_bt(
    const u16* __restrict__ A, const u16* __restrict__ B, u16* __restrict__ C,
    const float* __restrict__ bias, int M, int N, int K, int lda, int ldb, int ldc)
{
    __shared__ __align__(16) u16 As[128][64];
    __shared__ __align__(16) u16 Bs[128][64];

    const int nmt = (M + 127) >> 7;
    const int ntn = (N + 127) >> 7;
    // grouped rasterization, GROUP_M = 16 (A/B panel L2/L3 reuse)
    int bid = blockIdx.x;
    int per_grp = 16 * ntn;
    int g = bid / per_grp;
    int first = g * 16;
    int gsz = min(16, nmt - first);
    int rem = bid - g * per_grp;
    int mt = first + rem % gsz;
    int nt = rem / gsz;

    const int m0 = mt << 7, n0 = nt << 7;
    const int tid = threadIdx.x;
    const int wv = tid >> 6, ln = tid & 63;
    const int wr = wv >> 1, wc = wv & 1;

    f32x4 acc[4][4];
#pragma unroll
    for (int m = 0; m < 4; ++m)
#pragma unroll
        for (int n = 0; n < 4; ++n)
#pragma unroll
            for (int j = 0; j < 4; ++j) acc[m][n][j] = 0.f;

    const int lrow = ln & 15;
    const int koff = (ln >> 4) << 3;

    for (int k0 = 0; k0 < K; k0 += 64) {
#pragma unroll
        for (int r = 0; r < 4; ++r) {
            int c = r * 256 + wv * 64 + ln;   // 16B chunk id, 0..1023
            int row = c >> 3;
            int kc = (c & 7) << 3;
            int ga = m0 + row; ga = ga < M ? ga : M - 1;
            gload_lds16(A + (size_t)ga * lda + (k0 + kc),
                        (char*)&As[0][0] + (size_t)(r * 256 + wv * 64) * 16);
            int gb = n0 + row; gb = gb < N ? gb : N - 1;
            gload_lds16(B + (size_t)gb * ldb + (k0 + kc),
                        (char*)&Bs[0][0] + (size_t)(r * 256 + wv * 64) * 16);
        }
        __syncthreads();
#pragma unroll
        for (int kk = 0; kk < 2; ++kk) {
            bf16x8 af[4], bfr[4];
            const int krd = (kk << 5) + koff;
#pragma unroll
            for (int m = 0; m < 4; ++m)
                af[m] = *(const bf16x8*)&As[(wr << 6) + (m << 4) + lrow][krd];
#pragma unroll
            for (int n = 0; n < 4; ++n)
                bfr[n] = *(const bf16x8*)&Bs[(wc << 6) + (n << 4) + lrow][krd];
#pragma unroll
            for (int m = 0; m < 4; ++m)
#pragma unroll
                for (int n = 0; n < 4; ++n)
                    acc[m][n] = __builtin_amdgcn_mfma_f32_16x16x32_bf16(
                        af[m], bfr[n], acc[m][n], 0, 0, 0);
        }
        __syncthreads();
    }

    const int colb = ln & 15;
    const int rowb = (ln >> 4) << 2;
#pragma unroll
    for (int m = 0; m < 4; ++m) {
        int gr0 = m0 + (wr << 6) + (m << 4) + rowb;
#pragma unroll
        for (int n = 0; n < 4; ++n) {
            int gc = n0 + (wc << 6) + (n << 4) + colb;
            if (gc >= N) continue;
            float bv = (EPI == 1) ? bias[gc] : 0.f;
#pragma unroll
            for (int j = 0; j < 4; ++j) {
                int gr = gr0 + j;
                if (gr >= M) continue;
                float v = acc[m][n][j];
                if (EPI == 1) { v += bv; v = v > 0.f ? v : 0.f; }
                C[(size_t)gr * ldc + gc] = f2bf(v);
            }
        }
    }
}

// ---------------- fp32 -> bf16 convert (x), float4 granularity
__global__ void cvt_bf16(const float* __restrict__ in, u16* __restrict__ out, int n4)
{
    int i = blockIdx.x * 256 + threadIdx.x;
    if (i >= n4) return;
    float4 v = ((const float4*)in)[i];
    ushort4 o;
    o.x = f2bf(v.x); o.y = f2bf(v.y); o.z = f2bf(v.z); o.w = f2bf(v.w);
    ((ushort4*)out)[i] = o;
}

// ---------------- weight transpose+convert: out[n][k](bf16,ld=Kpad) = src[k][n](f32)
// two concatenated sources split at nsplit; k in [Kin,Kpad) zero-filled
__global__ void wtrans(const float* __restrict__ s0, const float* __restrict__ s1,
                       u16* __restrict__ out, int Kin, int Kpad, int N, int nsplit)
{
    __shared__ float t[32][33];
    int k0 = blockIdx.x << 5, n0 = blockIdx.y << 5;
    int tx = threadIdx.x, ty = threadIdx.y;
#pragma unroll
    for (int i = 0; i < 4; ++i) {
        int k = k0 + ty + (i << 3);
        int n = n0 + tx;
        float v = 0.f;
        if (k < Kin && n < N)
            v = (n < nsplit) ? s0[(size_t)k * nsplit + n]
                             : s1[(size_t)k * (N - nsplit) + (n - nsplit)];
        t[ty + (i << 3)][tx] = v;
    }
    __syncthreads();
#pragma unroll
    for (int i = 0; i < 4; ++i) {
        int n = n0 + ty + (i << 3);
        int k = k0 + tx;
        if (n < N && k < Kpad)
            out[(size_t)n * Kpad + k] = f2bf(t[tx][ty + (i << 3)]);
    }
}

// ---------------- edge degree count (fp32, exact integers)
__global__ void count_k(const int* __restrict__ dst, float* __restrict__ cnt, int ne)
{
    int e = blockIdx.x * 256 + threadIdx.x;
    if (e < ne) unsafeAtomicAdd(&cnt[dst[e]], 1.0f);
}

// ---------------- scatter-add aggregation: acc[dst][c] += y[src][c], c < ncols (y bf16)
__global__ void agg_k(const u16* __restrict__ y, const int* __restrict__ src,
                      const int* __restrict__ dst, float* __restrict__ acc,
                      int ldy, int ncols, int ne)
{
    int i = blockIdx.x * 256 + threadIdx.x;
    int nch = ncols >> 2;
    if (i >= ne * nch) return;
    int e = i / nch, c = (i - e * nch) << 2;
    int s = src[e], d = dst[e];
    ushort4 v = *(const ushort4*)&y[(size_t)s * ldy + c];
    float* p = &acc[(size_t)d * ncols + c];
    unsafeAtomicAdd(p + 0, bf2f(v.x));
    unsafeAtomicAdd(p + 1, bf2f(v.y));
    unsafeAtomicAdd(p + 2, bf2f(v.z));
    unsafeAtomicAdd(p + 3, bf2f(v.w));
}

// ---------------- h = BN(relu(acc/cnt + b1 + y1r)) -> bf16, K-padded to 1728 with zeros
__global__ void bn_h_k(const float* __restrict__ acc, const u16* __restrict__ y1,
                       const float* __restrict__ cnt, const float* __restrict__ b1,
                       const float* __restrict__ gam, const float* __restrict__ bet,
                       const float* __restrict__ mn, const float* __restrict__ vr,
                       u16* __restrict__ h)
{
    int i = blockIdx.x * 256 + threadIdx.x;
    const int CH = 1728 / 4;
    if (i >= NN * CH) return;
    int row = i / CH, c = (i - row * CH) << 2;
    ushort4 o; o.x = 0; o.y = 0; o.z = 0; o.w = 0;
    if (c < 1680) {
        float inv = 1.f / fmaxf(cnt[row], 1.f);
        float4 a = *(const float4*)&acc[(size_t)row * 1680 + c];
        ushort4 yr = *(const ushort4*)&y1[(size_t)row * 3360 + 1680 + c];
        float4 bb = *(const float4*)&b1[c];
        float4 g4 = *(const float4*)&gam[c];
        float4 be = *(const float4*)&bet[c];
        float4 m4 = *(const float4*)&mn[c];
        float4 v4 = *(const float4*)&vr[c];
        float t0 = fmaxf(a.x * inv + bb.x + bf2f(yr.x), 0.f);
        float t1 = fmaxf(a.y * inv + bb.y + bf2f(yr.y), 0.f);
        float t2 = fmaxf(a.z * inv + bb.z + bf2f(yr.z), 0.f);
        float t3 = fmaxf(a.w * inv + bb.w + bf2f(yr.w), 0.f);
        t0 = (t0 - m4.x) * rsqrtf(v4.x + BN_EPS) * g4.x + be.x;
        t1 = (t1 - m4.y) * rsqrtf(v4.y + BN_EPS) * g4.y + be.y;
        t2 = (t2 - m4.z) * rsqrtf(v4.z + BN_EPS) * g4.z + be.z;
        t3 = (t3 - m4.w) * rsqrtf(v4.w + BN_EPS) * g4.w + be.w;
        o.x = f2bf(t0); o.y = f2bf(t1); o.z = f2bf(t2); o.w = f2bf(t3);
    }
    *(ushort4*)&h[(size_t)row * 1728 + c] = o;
}

// ---------------- h2 = relu(acc2/cnt + b2 + y2r) -> bf16 [NN][640]
__global__ void h2_k(const float* __restrict__ acc2, const u16* __restrict__ y2,
                     const float* __restrict__ cnt, const float* __restrict__ b2,
                     u16* __restrict__ h2)
{
    int i = blockIdx.x * 256 + threadIdx.x;
    if (i >= NN * 160) return;
    int row = i / 160, c = (i - row * 160) << 2;
    float inv = 1.f / fmaxf(cnt[row], 1.f);
    float4 a = *(const float4*)&acc2[(size_t)row * 640 + c];
    ushort4 yr = *(const ushort4*)&y2[(size_t)row * 1280 + 640 + c];
    float4 bb = *(const float4*)&b2[c];
    ushort4 o;
    o.x = f2bf(fmaxf(a.x * inv + bb.x + bf2f(yr.x), 0.f));
    o.y = f2bf(fmaxf(a.y * inv + bb.y + bf2f(yr.y), 0.f));
    o.z = f2bf(fmaxf(a.z * inv + bb.z + bf2f(yr.z), 0.f));
    o.w = f2bf(fmaxf(a.w * inv + bb.w + bf2f(yr.w), 0.f));
    *(ushort4*)&h2[(size_t)row * 640 + c] = o;
}

// ---------------- final lin3: out[i][0:2] = o2[i][:] @ W(160x2) + b
__global__ void lin3_k(const u16* __restrict__ o2, const float* __restrict__ W,
                       const float* __restrict__ b, float* __restrict__ out)
{
    __shared__ float ws[320];
    for (int j = threadIdx.x; j < 320; j += 256) ws[j] = W[j];
    __syncthreads();
    int i = blockIdx.x * 256 + threadIdx.x;
    if (i >= NN) return;
    float a0 = b[0], a1 = b[1];
    const u16* row = o2 + (size_t)i * 160;
#pragma unroll
    for (int k8 = 0; k8 < 20; ++k8) {
        ushort4 v0 = *(const ushort4*)&row[k8 * 8];
        ushort4 v1 = *(const ushort4*)&row[k8 * 8 + 4];
        int kb = k8 * 8;
        float f;
        f = bf2f(v0.x); a0 += f * ws[(kb + 0) * 2]; a1 += f * ws[(kb + 0) * 2 + 1];
        f = bf2f(v0.y); a0 += f * ws[(kb + 1) * 2]; a1 += f * ws[(kb + 1) * 2 + 1];
        f = bf2f(v0.z); a0 += f * ws[(kb + 2) * 2]; a1 += f * ws[(kb + 2) * 2 + 1];
        f = bf2f(v0.w); a0 += f * ws[(kb + 3) * 2]; a1 += f * ws[(kb + 3) * 2 + 1];
        f = bf2f(v1.x); a0 += f * ws[(kb + 4) * 2]; a1 += f * ws[(kb + 4) * 2 + 1];
        f = bf2f(v1.y); a0 += f * ws[(kb + 5) * 2]; a1 += f * ws[(kb + 5) * 2 + 1];
        f = bf2f(v1.z); a0 += f * ws[(kb + 6) * 2]; a1 += f * ws[(kb + 6) * 2 + 1];
        f = bf2f(v1.w); a0 += f * ws[(kb + 7) * 2]; a1 += f * ws[(kb + 7) * 2 + 1];
    }
    out[(size_t)i * 2 + 0] = a0;
    out[(size_t)i * 2 + 1] = a1;
}

extern "C" void kernel_launch(void* const* d_in, const int* in_sizes, int n_in,
                              void* d_out, int out_size, void* d_ws, size_t ws_size,
                              hipStream_t stream)
{
    const float* x     = (const float*)d_in[0];
    const float* W1l   = (const float*)d_in[1];
    const float* b1    = (const float*)d_in[2];
    const float* W1r   = (const float*)d_in[3];
    const float* W2l   = (const float*)d_in[4];
    const float* b2    = (const float*)d_in[5];
    const float* W2r   = (const float*)d_in[6];
    const float* gam   = (const float*)d_in[7];
    const float* bet   = (const float*)d_in[8];
    const float* bmean = (const float*)d_in[9];
    const float* bvar  = (const float*)d_in[10];
    const float* l1W   = (const float*)d_in[11];
    const float* l1b   = (const float*)d_in[12];
    const float* l2W   = (const float*)d_in[13];
    const float* l2b   = (const float*)d_in[14];
    const float* l3W   = (const float*)d_in[15];
    const float* l3b   = (const float*)d_in[16];
    const int*   ei    = (const int*)d_in[17];
    const int* src = ei, * dst = ei + NE;

    char* ws = (char*)d_ws;
    // liveness-overlaid workspace layout (total ~376 MB)
    u16*   y1   = (u16*)(ws + 0);            // [NN][3360] bf16, 134.4MB
    u16*   y2   = (u16*)(ws + 0);            // [NN][1280] bf16 (after y1 dead)
    u16*   o1   = (u16*)(ws + 0);            // [NN][320]  bf16 (after y2 dead)
    u16*   o2   = (u16*)(ws + 16000000);     // [NN][160]  bf16
    u16*   xbf  = (u16*)(ws + 136000000);    // [NN][5120] bf16, 204.8MB
    u16*   hbuf = (u16*)(ws + 136000000);    // [NN][1728] bf16 (after GEMM1)
    u16*   h2   = (u16*)(ws + 136000000);    // [NN][640]  bf16 (after GEMM2)
    float* acc1 = (float*)(ws + 206000000);  // [NN][1680] f32 (in dead xbf region)
    float* acc2 = (float*)(ws + 206000000);  // [NN][640]  f32 (after acc1 dead)
    u16*   w1T  = (u16*)(ws + 341000000);    // [3360][5120] bf16, 34.4MB
    u16*   w2T  = (u16*)(ws + 341000000);    // [1280][1728] bf16 (after GEMM1)
    u16*   l1T  = (u16*)(ws + 346000000);    // [320][640] bf16
    u16*   l2T  = (u16*)(ws + 347000000);    // [160][320] bf16
    float* cnt  = (float*)(ws + 376000000);  // [NN] f32

    // 0) degree counts
    hipMemsetAsync(cnt, 0, NN * sizeof(float), stream);
    count_k<<<(NE + 255) / 256, 256, 0, stream>>>(dst, cnt, NE);

    // 1) x -> bf16 ; W1 -> [3360][5120] bf16 (transposed, concat [W1l|W1r])
    {
        int n4 = NN * 5120 / 4;
        cvt_bf16<<<(n4 + 255) / 256, 256, 0, stream>>>(x, xbf, n4);
    }
    wtrans<<<dim3(160, 105), dim3(32, 8), 0, stream>>>(W1l, W1r, w1T, 5120, 5120, 3360, 1680);

    // 2) GEMM1: y1[NN][3360] = xbf @ w1T^T
    gemm_bt<0><<<157 * 27, 256, 0, stream>>>(xbf, w1T, y1, nullptr,
                                             NN, 3360, 5120, 5120, 5120, 3360);

    // 3) aggregate y1l into acc1
    hipMemsetAsync(acc1, 0, (size_t)NN * 1680 * 4, stream);
    agg_k<<<(NE * 420 + 255) / 256, 256, 0, stream>>>(y1, src, dst, acc1, 3360, 1680, NE);

    // 4) h = BN(relu(acc1/cnt + b1 + y1r)) -> hbuf (zero-padded to K=1728)
    bn_h_k<<<(NN * 432 + 255) / 256, 256, 0, stream>>>(acc1, y1, cnt, b1, gam, bet, bmean, bvar, hbuf);

    // 5) W2 -> [1280][1728] bf16 (zero-padded K)
    wtrans<<<dim3(54, 40), dim3(32, 8), 0, stream>>>(W2l, W2r, w2T, 1680, 1728, 1280, 640);

    // 6) GEMM2: y2[NN][1280] = hbuf @ w2T^T
    gemm_bt<0><<<157 * 10, 256, 0, stream>>>(hbuf, w2T, y2, nullptr,
                                             NN, 1280, 1728, 1728, 1728, 1280);

    // 7) aggregate y2l into acc2
    hipMemsetAsync(acc2, 0, (size_t)NN * 640 * 4, stream);
    agg_k<<<(NE * 160 + 255) / 256, 256, 0, stream>>>(y2, src, dst, acc2, 1280, 640, NE);

    // 8) h2 = relu(acc2/cnt + b2 + y2r)
    h2_k<<<(NN * 160 + 255) / 256, 256, 0, stream>>>(acc2, y2, cnt, b2, h2);

    // 9) lin1/lin2 weights transposed
    wtrans<<<dim3(20, 10), dim3(32, 8), 0, stream>>>(l1W, l1W, l1T, 640, 640, 320, 320);
    wtrans<<<dim3(10, 5), dim3(32, 8), 0, stream>>>(l2W, l2W, l2T, 320, 320, 160, 160);

    // 10) GEMM3: o1 = relu(h2 @ l1T^T + l1b)   [NN][320]
    gemm_bt<1><<<157 * 3, 256, 0, stream>>>(h2, l1T, o1, l1b,
                                            NN, 320, 640, 640, 640, 320);

    // 11) GEMM4: o2 = relu(o1 @ l2T^T + l2b)   [NN][160]
    gemm_bt<1><<<157 * 2, 256, 0, stream>>>(o1, l2T, o2, l2b,
                                            NN, 160, 320, 320, 320, 160);

    // 12) lin3 -> out [NN][2] fp32
    lin3_k<<<(NN + 255) / 256, 256, 0, stream>>>(o2, l3W, l3b, (float*)d_out);
}

// Round 2
// 2036.262 us; speedup vs baseline: 1.1792x; 1.1792x over previous
//
#include <hip/hip_runtime.h>
#include <stdint.h>

#define NN 20000
#define NE 32000
#define BN_EPS 1e-5f

typedef __attribute__((ext_vector_type(8))) __bf16 bf16x8;
typedef __attribute__((ext_vector_type(4))) float f32x4;
typedef unsigned short u16;
typedef uint32_t u32;

__device__ __forceinline__ u16 f2bf(float f) {
    u32 u = __float_as_uint(f);
    u += 0x7FFFu + ((u >> 16) & 1u);
    return (u16)(u >> 16);
}
__device__ __forceinline__ float bf2f(u16 u) {
    return __uint_as_float(((u32)u) << 16);
}

__device__ __forceinline__ void gload_lds16(const void* g, void* l) {
    __builtin_amdgcn_global_load_lds(
        (const __attribute__((address_space(1))) void*)g,
        (__attribute__((address_space(3))) void*)(uintptr_t)l,
        16, 0, 0);
}

// ================== 256x256 8-phase GEMM (T1+T2+T3+T4+T5) ==================
// C[M][N](bf16) = A[M][K](bf16) * B^T  (B stored [N][K] bf16). K % 128 == 0.
// 512 threads = 8 waves (2M x 4N). Per-wave out 128x64 as acc[8][4] frags at
// rows m*32+wr*16, cols n*64+wc*16. LDS st-swizzle: byte ^= ((row&7)<<4),
// inverse pre-applied on the global source of global_load_lds (linear dest).

#define LDSRD(base, r, cb) (*(const bf16x8*)((const char*)(base) + (r)*128 + (cb)))

#define DS_A(apb, qm) do { \
  _Pragma("unroll") for (int m4_ = 0; m4_ < 4; ++m4_) { \
    int r_ = (qm)*128 + m4_*32 + wr16 + lrow; \
    aR[m4_][0] = LDSRD(apb, r_, cb0); \
    aR[m4_][1] = LDSRD(apb, r_, cb1); \
  } } while (0)

#define DS_B(bpb, qn) do { \
  _Pragma("unroll") for (int n2_ = 0; n2_ < 2; ++n2_) { \
    int n_ = (qn)*2 + n2_; \
    int r_ = n_*64 + wc16 + lrow; \
    bR[n_][0] = LDSRD(bpb, r_, cb0); \
    bR[n_][1] = LDSRD(bpb, r_, cb1); \
  } } while (0)

#define MM(qm, qn) do { \
  _Pragma("unroll") for (int m4_ = 0; m4_ < 4; ++m4_) \
  _Pragma("unroll") for (int n2_ = 0; n2_ < 2; ++n2_) { \
    int mi_ = (qm)*4 + m4_, ni_ = (qn)*2 + n2_; \
    acc[mi_][ni_] = __builtin_amdgcn_mfma_f32_16x16x32_bf16(aR[m4_][0], bR[ni_][0], acc[mi_][ni_], 0, 0, 0); \
    acc[mi_][ni_] = __builtin_amdgcn_mfma_f32_16x16x32_bf16(aR[m4_][1], bR[ni_][1], acc[mi_][ni_], 0, 0, 0); \
  } } while (0)

#define STG(Mat, ld, r0, rmax, t, ldsb) do { \
  int ks_ = (t) * 64; if (ks_ > Km64) ks_ = Km64; \
  int ra_ = (r0) + row0;      ra_ = ra_ < (rmax) ? ra_ : (rmax) - 1; \
  int rb_ = (r0) + row0 + 64; rb_ = rb_ < (rmax) ? rb_ : (rmax) - 1; \
  char* d_ = (char*)(ldsb) + dstoff; \
  gload_lds16((Mat) + (size_t)ra_ * (ld) + ks_ + kel, d_); \
  gload_lds16((Mat) + (size_t)rb_ * (ld) + ks_ + kel, d_ + 8192); \
} while (0)

#define SA(b, ha, t) STG(A, lda, m0 + (ha)*128, M, t, &As[b][(ha)*128][0])
#define SB(b, hb, t) STG(B, ldb, n0 + (hb)*128, N, t, &Bs[b][(hb)*128][0])

#define PHASE_TOP() do { __builtin_amdgcn_s_barrier(); \
  asm volatile("s_waitcnt lgkmcnt(0)" ::: "memory"); \
  __builtin_amdgcn_s_setprio(1); } while (0)
#define PHASE_END() do { __builtin_amdgcn_s_setprio(0); \
  __builtin_amdgcn_s_barrier(); } while (0)
#define PHASE_END_VM() do { __builtin_amdgcn_s_setprio(0); \
  asm volatile("s_waitcnt vmcnt(6)" ::: "memory"); \
  __builtin_amdgcn_s_barrier(); } while (0)

__global__ __launch_bounds__(512, 2) void gemm256(
    const u16* __restrict__ A, const u16* __restrict__ B, u16* __restrict__ C,
    int M, int N, int K, int lda, int ldb, int ldc)
{
    __shared__ __align__(16) u16 As[2][256][64];
    __shared__ __align__(16) u16 Bs[2][256][64];

    const int nmt = (M + 255) >> 8;
    const int ntn = (N + 255) >> 8;
    const int nwg = nmt * ntn;

    // bijective XCD swizzle (m204) then grouped-M raster (GROUP=8)
    int bid = blockIdx.x;
    int q8 = nwg >> 3, r8 = nwg & 7;
    int xcd = bid & 7, lid = bid >> 3;
    int wgid = (xcd < r8 ? xcd * (q8 + 1) : r8 * (q8 + 1) + (xcd - r8) * q8) + lid;
    int per = ntn << 3;
    int g = wgid / per;
    int first = g << 3;
    int gsz = nmt - first; gsz = gsz < 8 ? gsz : 8;
    int rem = wgid - g * per;
    int mt = first + rem % gsz;
    int nt = rem / gsz;

    const int m0 = mt << 8, n0 = nt << 8;
    const int tid = threadIdx.x;
    const int wid = tid >> 6, ln = tid & 63;
    const int wr = wid >> 2, wc = wid & 3;
    const int lrow = ln & 15, khi = ln >> 4;
    const int wr16 = wr << 4, wc16 = wc << 4;
    const int cb0 = (khi << 4) ^ ((lrow & 7) << 4);
    const int cb1 = cb0 ^ 64;
    const int row0 = tid >> 3;
    const int kel = ((tid & 7) ^ (row0 & 7)) << 3;
    const int dstoff = (tid & 448) << 4;
    const int Km64 = K - 64;

    f32x4 acc[8][4];
#pragma unroll
    for (int m = 0; m < 8; ++m)
#pragma unroll
        for (int n = 0; n < 4; ++n)
#pragma unroll
            for (int j = 0; j < 4; ++j) acc[m][n][j] = 0.f;
    bf16x8 aR[4][2], bR[4][2];

    // prologue: tile0 fully (A0,B0,B1,A1), then tile1 (A0,B0,B1)
    SA(0, 0, 0); SB(0, 0, 0); SB(0, 1, 0); SA(0, 1, 0);
    SA(1, 0, 1); SB(1, 0, 1); SB(1, 1, 1);
    asm volatile("s_waitcnt vmcnt(6)" ::: "memory");
    __builtin_amdgcn_s_barrier();

    const int nit = K >> 7;
    for (int it = 0; it < nit; ++it) {
        const int t1 = 2 * it + 1, t2 = 2 * it + 2, t3 = 2 * it + 3;
        // p0: reads buf0 A-half0/B-half0; stages A1(t1)->buf1
        DS_A(&As[0][0][0], 0); DS_B(&Bs[0][0][0], 0);
        SA(1, 1, t1);
        PHASE_TOP(); MM(0, 0); PHASE_END();
        // p1: reads buf0 B-half1; stages A0(t2)->buf0
        DS_B(&Bs[0][0][0], 1);
        SA(0, 0, t2);
        PHASE_TOP(); MM(0, 1); PHASE_END();
        // p2: reads buf0 A-half1; stages B0(t2)->buf0
        DS_A(&As[0][0][0], 1);
        SB(0, 0, t2);
        PHASE_TOP(); MM(1, 1); PHASE_END();
        // p3: stages B1(t2)->buf0; counted vmcnt
        SB(0, 1, t2);
        __builtin_amdgcn_s_barrier();
        __builtin_amdgcn_s_setprio(1);
        MM(1, 0);
        PHASE_END_VM();
        // p4: reads buf1; stages A1(t2)->buf0
        DS_A(&As[1][0][0], 0); DS_B(&Bs[1][0][0], 0);
        SA(0, 1, t2);
        PHASE_TOP(); MM(0, 0); PHASE_END();
        // p5: stages A0(t3)->buf1
        DS_B(&Bs[1][0][0], 1);
        SA(1, 0, t3);
        PHASE_TOP(); MM(0, 1); PHASE_END();
        // p6: stages B0(t3)->buf1
        DS_A(&As[1][0][0], 1);
        SB(1, 0, t3);
        PHASE_TOP(); MM(1, 1); PHASE_END();
        // p7: stages B1(t3)->buf1; counted vmcnt
        SB(1, 1, t3);
        __builtin_amdgcn_s_barrier();
        __builtin_amdgcn_s_setprio(1);
        MM(1, 0);
        PHASE_END_VM();
    }

    // epilogue: C/D frag layout col=ln&15, row=(ln>>4)*4+j
#pragma unroll
    for (int m = 0; m < 8; ++m) {
        int gr0 = m0 + m * 32 + wr16 + (khi << 2);
#pragma unroll
        for (int n = 0; n < 4; ++n) {
            int gc = n0 + n * 64 + wc16 + lrow;
            if (gc >= N) continue;
#pragma unroll
            for (int j = 0; j < 4; ++j) {
                int gr = gr0 + j;
                if (gr >= M) continue;
                C[(size_t)gr * ldc + gc] = f2bf(acc[m][n][j]);
            }
        }
    }
}

// ================== 128x128 GEMM (kept for small layers) ==================
template <int EPI>
__global__ __launch_bounds__(256, 2) void gemm_bt(
    const u16* __restrict__ A, const u16* __restrict__ B, u16* __restrict__ C,
    const float* __restrict__ bias, int M, int N, int K, int lda, int ldb, int ldc)
{
    __shared__ __align__(16) u16 As[128][64];
    __shared__ __align__(16) u16 Bs[128][64];

    const int nmt = (M + 127) >> 7;
    const int ntn = (N + 127) >> 7;
    int bid = blockIdx.x;
    int per_grp = 16 * ntn;
    int g = bid / per_grp;
    int first = g * 16;
    int gsz = min(16, nmt - first);
    int rem = bid - g * per_grp;
    int mt = first + rem % gsz;
    int nt = rem / gsz;

    const int m0 = mt << 7, n0 = nt << 7;
    const int tid = threadIdx.x;
    const int wv = tid >> 6, ln = tid & 63;
    const int wr = wv >> 1, wc = wv & 1;

    f32x4 acc[4][4];
#pragma unroll
    for (int m = 0; m < 4; ++m)
#pragma unroll
        for (int n = 0; n < 4; ++n)
#pragma unroll
            for (int j = 0; j < 4; ++j) acc[m][n][j] = 0.f;

    const int lrow = ln & 15;
    const int koff = (ln >> 4) << 3;

    for (int k0 = 0; k0 < K; k0 += 64) {
#pragma unroll
        for (int r = 0; r < 4; ++r) {
            int c = r * 256 + wv * 64 + ln;
            int row = c >> 3;
            int kc = (c & 7) << 3;
            int ga = m0 + row; ga = ga < M ? ga : M - 1;
            gload_lds16(A + (size_t)ga * lda + (k0 + kc),
                        (char*)&As[0][0] + (size_t)(r * 256 + wv * 64) * 16);
            int gb = n0 + row; gb = gb < N ? gb : N - 1;
            gload_lds16(B + (size_t)gb * ldb + (k0 + kc),
                        (char*)&Bs[0][0] + (size_t)(r * 256 + wv * 64) * 16);
        }
        __syncthreads();
#pragma unroll
        for (int kk = 0; kk < 2; ++kk) {
            bf16x8 af[4], bfr[4];
            const int krd = (kk << 5) + koff;
#pragma unroll
            for (int m = 0; m < 4; ++m)
                af[m] = *(const bf16x8*)&As[(wr << 6) + (m << 4) + lrow][krd];
#pragma unroll
            for (int n = 0; n < 4; ++n)
                bfr[n] = *(const bf16x8*)&Bs[(wc << 6) + (n << 4) + lrow][krd];
#pragma unroll
            for (int m = 0; m < 4; ++m)
#pragma unroll
                for (int n = 0; n < 4; ++n)
                    acc[m][n] = __builtin_amdgcn_mfma_f32_16x16x32_bf16(
                        af[m], bfr[n], acc[m][n], 0, 0, 0);
        }
        __syncthreads();
    }

    const int colb = ln & 15;
    const int rowb = (ln >> 4) << 2;
#pragma unroll
    for (int m = 0; m < 4; ++m) {
        int gr0 = m0 + (wr << 6) + (m << 4) + rowb;
#pragma unroll
        for (int n = 0; n < 4; ++n) {
            int gc = n0 + (wc << 6) + (n << 4) + colb;
            if (gc >= N) continue;
            float bv = (EPI == 1) ? bias[gc] : 0.f;
#pragma unroll
            for (int j = 0; j < 4; ++j) {
                int gr = gr0 + j;
                if (gr >= M) continue;
                float v = acc[m][n][j];
                if (EPI == 1) { v += bv; v = v > 0.f ? v : 0.f; }
                C[(size_t)gr * ldc + gc] = f2bf(v);
            }
        }
    }
}

// ---------------- fp32 -> bf16 convert
__global__ void cvt_bf16(const float* __restrict__ in, u16* __restrict__ out, int n4)
{
    int i = blockIdx.x * 256 + threadIdx.x;
    if (i >= n4) return;
    float4 v = ((const float4*)in)[i];
    ushort4 o;
    o.x = f2bf(v.x); o.y = f2bf(v.y); o.z = f2bf(v.z); o.w = f2bf(v.w);
    ((ushort4*)out)[i] = o;
}

// ---------------- weight transpose+convert: out[n][k](bf16,ld=Kpad) = src[k][n](f32)
__global__ void wtrans(const float* __restrict__ s0, const float* __restrict__ s1,
                       u16* __restrict__ out, int Kin, int Kpad, int N, int nsplit)
{
    __shared__ float t[32][33];
    int k0 = blockIdx.x << 5, n0 = blockIdx.y << 5;
    int tx = threadIdx.x, ty = threadIdx.y;
#pragma unroll
    for (int i = 0; i < 4; ++i) {
        int k = k0 + ty + (i << 3);
        int n = n0 + tx;
        float v = 0.f;
        if (k < Kin && n < N)
            v = (n < nsplit) ? s0[(size_t)k * nsplit + n]
                             : s1[(size_t)k * (N - nsplit) + (n - nsplit)];
        t[ty + (i << 3)][tx] = v;
    }
    __syncthreads();
#pragma unroll
    for (int i = 0; i < 4; ++i) {
        int n = n0 + ty + (i << 3);
        int k = k0 + tx;
        if (n < N && k < Kpad)
            out[(size_t)n * Kpad + k] = f2bf(t[tx][ty + (i << 3)]);
    }
}

// ---------------- edge degree count
__global__ void count_k(const int* __restrict__ dst, float* __restrict__ cnt, int ne)
{
    int e = blockIdx.x * 256 + threadIdx.x;
    if (e < ne) unsafeAtomicAdd(&cnt[dst[e]], 1.0f);
}

// ---------------- scatter-add aggregation
__global__ void agg_k(const u16* __restrict__ y, const int* __restrict__ src,
                      const int* __restrict__ dst, float* __restrict__ acc,
                      int ldy, int ncols, int ne)
{
    int i = blockIdx.x * 256 + threadIdx.x;
    int nch = ncols >> 2;
    if (i >= ne * nch) return;
    int e = i / nch, c = (i - e * nch) << 2;
    int s = src[e], d = dst[e];
    ushort4 v = *(const ushort4*)&y[(size_t)s * ldy + c];
    float* p = &acc[(size_t)d * ncols + c];
    unsafeAtomicAdd(p + 0, bf2f(v.x));
    unsafeAtomicAdd(p + 1, bf2f(v.y));
    unsafeAtomicAdd(p + 2, bf2f(v.z));
    unsafeAtomicAdd(p + 3, bf2f(v.w));
}

// ---------------- h = BN(relu(acc/cnt + b1 + y1r)) -> bf16, K-padded to 1792
__global__ void bn_h_k(const float* __restrict__ acc, const u16* __restrict__ y1,
                       const float* __restrict__ cnt, const float* __restrict__ b1,
                       const float* __restrict__ gam, const float* __restrict__ bet,
                       const float* __restrict__ mn, const float* __restrict__ vr,
                       u16* __restrict__ h)
{
    int i = blockIdx.x * 256 + threadIdx.x;
    const int CH = 1792 / 4;
    if (i >= NN * CH) return;
    int row = i / CH, c = (i - row * CH) << 2;
    ushort4 o; o.x = 0; o.y = 0; o.z = 0; o.w = 0;
    if (c < 1680) {
        float inv = 1.f / fmaxf(cnt[row], 1.f);
        float4 a = *(const float4*)&acc[(size_t)row * 1680 + c];
        ushort4 yr = *(const ushort4*)&y1[(size_t)row * 3360 + 1680 + c];
        float4 bb = *(const float4*)&b1[c];
        float4 g4 = *(const float4*)&gam[c];
        float4 be = *(const float4*)&bet[c];
        float4 m4 = *(const float4*)&mn[c];
        float4 v4 = *(const float4*)&vr[c];
        float t0 = fmaxf(a.x * inv + bb.x + bf2f(yr.x), 0.f);
        float t1 = fmaxf(a.y * inv + bb.y + bf2f(yr.y), 0.f);
        float t2 = fmaxf(a.z * inv + bb.z + bf2f(yr.z), 0.f);
        float t3 = fmaxf(a.w * inv + bb.w + bf2f(yr.w), 0.f);
        t0 = (t0 - m4.x) * rsqrtf(v4.x + BN_EPS) * g4.x + be.x;
        t1 = (t1 - m4.y) * rsqrtf(v4.y + BN_EPS) * g4.y + be.y;
        t2 = (t2 - m4.z) * rsqrtf(v4.z + BN_EPS) * g4.z + be.z;
        t3 = (t3 - m4.w) * rsqrtf(v4.w + BN_EPS) * g4.w + be.w;
        o.x = f2bf(t0); o.y = f2bf(t1); o.z = f2bf(t2); o.w = f2bf(t3);
    }
    *(ushort4*)&h[(size_t)row * 1792 + c] = o;
}

// ---------------- h2 = relu(acc2/cnt + b2 + y2r) -> bf16 [NN][640]
__global__ void h2_k(const float* __restrict__ acc2, const u16* __restrict__ y2,
                     const float* __restrict__ cnt, const float* __restrict__ b2,
                     u16* __restrict__ h2)
{
    int i = blockIdx.x * 256 + threadIdx.x;
    if (i >= NN * 160) return;
    int row = i / 160, c = (i - row * 160) << 2;
    float inv = 1.f / fmaxf(cnt[row], 1.f);
    float4 a = *(const float4*)&acc2[(size_t)row * 640 + c];
    ushort4 yr = *(const ushort4*)&y2[(size_t)row * 1280 + 640 + c];
    float4 bb = *(const float4*)&b2[c];
    ushort4 o;
    o.x = f2bf(fmaxf(a.x * inv + bb.x + bf2f(yr.x), 0.f));
    o.y = f2bf(fmaxf(a.y * inv + bb.y + bf2f(yr.y), 0.f));
    o.z = f2bf(fmaxf(a.z * inv + bb.z + bf2f(yr.z), 0.f));
    o.w = f2bf(fmaxf(a.w * inv + bb.w + bf2f(yr.w), 0.f));
    *(ushort4*)&h2[(size_t)row * 640 + c] = o;
}

// ---------------- final lin3
__global__ void lin3_k(const u16* __restrict__ o2, const float* __restrict__ W,
                       const float* __restrict__ b, float* __restrict__ out)
{
    __shared__ float ws[320];
    for (int j = threadIdx.x; j < 320; j += 256) ws[j] = W[j];
    __syncthreads();
    int i = blockIdx.x * 256 + threadIdx.x;
    if (i >= NN) return;
    float a0 = b[0], a1 = b[1];
    const u16* row = o2 + (size_t)i * 160;
#pragma unroll
    for (int k8 = 0; k8 < 20; ++k8) {
        ushort4 v0 = *(const ushort4*)&row[k8 * 8];
        ushort4 v1 = *(const ushort4*)&row[k8 * 8 + 4];
        int kb = k8 * 8;
        float f;
        f = bf2f(v0.x); a0 += f * ws[(kb + 0) * 2]; a1 += f * ws[(kb + 0) * 2 + 1];
        f = bf2f(v0.y); a0 += f * ws[(kb + 1) * 2]; a1 += f * ws[(kb + 1) * 2 + 1];
        f = bf2f(v0.z); a0 += f * ws[(kb + 2) * 2]; a1 += f * ws[(kb + 2) * 2 + 1];
        f = bf2f(v0.w); a0 += f * ws[(kb + 3) * 2]; a1 += f * ws[(kb + 3) * 2 + 1];
        f = bf2f(v1.x); a0 += f * ws[(kb + 4) * 2]; a1 += f * ws[(kb + 4) * 2 + 1];
        f = bf2f(v1.y); a0 += f * ws[(kb + 5) * 2]; a1 += f * ws[(kb + 5) * 2 + 1];
        f = bf2f(v1.z); a0 += f * ws[(kb + 6) * 2]; a1 += f * ws[(kb + 6) * 2 + 1];
        f = bf2f(v1.w); a0 += f * ws[(kb + 7) * 2]; a1 += f * ws[(kb + 7) * 2 + 1];
    }
    out[(size_t)i * 2 + 0] = a0;
    out[(size_t)i * 2 + 1] = a1;
}

extern "C" void kernel_launch(void* const* d_in, const int* in_sizes, int n_in,
                              void* d_out, int out_size, void* d_ws, size_t ws_size,
                              hipStream_t stream)
{
    const float* x     = (const float*)d_in[0];
    const float* W1l   = (const float*)d_in[1];
    const float* b1    = (const float*)d_in[2];
    const float* W1r   = (const float*)d_in[3];
    const float* W2l   = (const float*)d_in[4];
    const float* b2    = (const float*)d_in[5];
    const float* W2r   = (const float*)d_in[6];
    const float* gam   = (const float*)d_in[7];
    const float* bet   = (const float*)d_in[8];
    const float* bmean = (const float*)d_in[9];
    const float* bvar  = (const float*)d_in[10];
    const float* l1W   = (const float*)d_in[11];
    const float* l1b   = (const float*)d_in[12];
    const float* l2W   = (const float*)d_in[13];
    const float* l2b   = (const float*)d_in[14];
    const float* l3W   = (const float*)d_in[15];
    const float* l3b   = (const float*)d_in[16];
    const int*   ei    = (const int*)d_in[17];
    const int* src = ei, * dst = ei + NE;

    char* ws = (char*)d_ws;
    // liveness-overlaid workspace layout
    u16*   y1   = (u16*)(ws + 0);            // [NN][3360] bf16
    u16*   y2   = (u16*)(ws + 0);            // [NN][1280] bf16 (after y1 dead)
    u16*   o1   = (u16*)(ws + 0);            // [NN][320]  bf16 (after y2 dead)
    u16*   o2   = (u16*)(ws + 16000000);     // [NN][160]  bf16
    u16*   xbf  = (u16*)(ws + 136000000);    // [NN][5120] bf16
    u16*   hbuf = (u16*)(ws + 136000000);    // [NN][1792] bf16 (after GEMM1; ends 207.7M)
    u16*   h2   = (u16*)(ws + 136000000);    // [NN][640]  bf16 (after GEMM2)
    float* acc1 = (float*)(ws + 210000000);  // [NN][1680] f32 (in dead xbf region; ends 344.4M)
    float* acc2 = (float*)(ws + 210000000);  // [NN][640]  f32 (after acc1 dead)
    u16*   w1T  = (u16*)(ws + 341000000);    // [3360][5120] bf16 (dead before acc1 memset)
    u16*   w2T  = (u16*)(ws + 341000000);    // [1280][1792] bf16 (after acc1 dead)
    u16*   l1T  = (u16*)(ws + 346000000);    // [320][640] bf16
    u16*   l2T  = (u16*)(ws + 347000000);    // [160][320] bf16
    float* cnt  = (float*)(ws + 376000000);  // [NN] f32

    // 0) degree counts
    hipMemsetAsync(cnt, 0, NN * sizeof(float), stream);
    count_k<<<(NE + 255) / 256, 256, 0, stream>>>(dst, cnt, NE);

    // 1) x -> bf16 ; W1 -> [3360][5120] bf16 (transposed, concat [W1l|W1r])
    {
        int n4 = NN * 5120 / 4;
        cvt_bf16<<<(n4 + 255) / 256, 256, 0, stream>>>(x, xbf, n4);
    }
    wtrans<<<dim3(160, 105), dim3(32, 8), 0, stream>>>(W1l, W1r, w1T, 5120, 5120, 3360, 1680);

    // 2) GEMM1 (8-phase 256^2): y1[NN][3360] = xbf @ w1T^T   (79 x 14 tiles)
    gemm256<<<79 * 14, 512, 0, stream>>>(xbf, w1T, y1, NN, 3360, 5120, 5120, 5120, 3360);

    // 3) aggregate y1l into acc1
    hipMemsetAsync(acc1, 0, (size_t)NN * 1680 * 4, stream);
    agg_k<<<(NE * 420 + 255) / 256, 256, 0, stream>>>(y1, src, dst, acc1, 3360, 1680, NE);

    // 4) h = BN(relu(acc1/cnt + b1 + y1r)) -> hbuf (zero-padded to K=1792)
    bn_h_k<<<(NN * 448 + 255) / 256, 256, 0, stream>>>(acc1, y1, cnt, b1, gam, bet, bmean, bvar, hbuf);

    // 5) W2 -> [1280][1792] bf16 (zero-padded K)
    wtrans<<<dim3(56, 40), dim3(32, 8), 0, stream>>>(W2l, W2r, w2T, 1680, 1792, 1280, 640);

    // 6) GEMM2 (8-phase 256^2): y2[NN][1280] = hbuf @ w2T^T  (79 x 5 tiles)
    gemm256<<<79 * 5, 512, 0, stream>>>(hbuf, w2T, y2, NN, 1280, 1792, 1792, 1792, 1280);

    // 7) aggregate y2l into acc2
    hipMemsetAsync(acc2, 0, (size_t)NN * 640 * 4, stream);
    agg_k<<<(NE * 160 + 255) / 256, 256, 0, stream>>>(y2, src, dst, acc2, 1280, 640, NE);

    // 8) h2 = relu(acc2/cnt + b2 + y2r)
    h2_k<<<(NN * 160 + 255) / 256, 256, 0, stream>>>(acc2, y2, cnt, b2, h2);

    // 9) lin1/lin2 weights transposed
    wtrans<<<dim3(20, 10), dim3(32, 8), 0, stream>>>(l1W, l1W, l1T, 640, 640, 320, 320);
    wtrans<<<dim3(10, 5), dim3(32, 8), 0, stream>>>(l2W, l2W, l2T, 320, 320, 160, 160);

    // 10) GEMM3: o1 = relu(h2 @ l1T^T + l1b)   [NN][320]
    gemm_bt<1><<<157 * 3, 256, 0, stream>>>(h2, l1T, o1, l1b,
                                            NN, 320, 640, 640, 640, 320);

    // 11) GEMM4: o2 = relu(o1 @ l2T^T + l2b)   [NN][160]
    gemm_bt<1><<<157 * 2, 256, 0, stream>>>(o1, l2T, o2, l2b,
                                            NN, 160, 320, 320, 320, 160);

    // 12) lin3 -> out [NN][2] fp32
    lin3_k<<<(NN + 255) / 256, 256, 0, stream>>>(o2, l3W, l3b, (float*)d_out);
}

// Round 3
// 1102.366 us; speedup vs baseline: 2.1781x; 1.8472x over previous
//
#include <hip/hip_runtime.h>
#include <stdint.h>

#define NN 20000
#define NE 32000
#define BN_EPS 1e-5f

typedef __attribute__((ext_vector_type(8))) __bf16 bf16x8;
typedef __attribute__((ext_vector_type(4))) float f32x4;
typedef unsigned short u16;
typedef uint32_t u32;

__device__ __forceinline__ u16 f2bf(float f) {
    u32 u = __float_as_uint(f);
    u += 0x7FFFu + ((u >> 16) & 1u);
    return (u16)(u >> 16);
}
__device__ __forceinline__ float bf2f(u16 u) {
    return __uint_as_float(((u32)u) << 16);
}

__device__ __forceinline__ void gload_lds16(const void* g, void* l) {
    __builtin_amdgcn_global_load_lds(
        (const __attribute__((address_space(1))) void*)g,
        (__attribute__((address_space(3))) void*)(uintptr_t)l,
        16, 0, 0);
}

// ================== 256x256 8-phase GEMM (T1+T2+T3+T4+T5) ==================
// C[M][N](bf16) = A[M][K](bf16) * B^T  (B stored [N][K] bf16). K % 128 == 0.

#define LDSRD(base, r, cb) (*(const bf16x8*)((const char*)(base) + (r)*128 + (cb)))

#define DS_A(apb, qm) do { \
  _Pragma("unroll") for (int m4_ = 0; m4_ < 4; ++m4_) { \
    int r_ = (qm)*128 + m4_*32 + wr16 + lrow; \
    aR[m4_][0] = LDSRD(apb, r_, cb0); \
    aR[m4_][1] = LDSRD(apb, r_, cb1); \
  } } while (0)

#define DS_B(bpb, qn) do { \
  _Pragma("unroll") for (int n2_ = 0; n2_ < 2; ++n2_) { \
    int n_ = (qn)*2 + n2_; \
    int r_ = n_*64 + wc16 + lrow; \
    bR[n_][0] = LDSRD(bpb, r_, cb0); \
    bR[n_][1] = LDSRD(bpb, r_, cb1); \
  } } while (0)

#define MM(qm, qn) do { \
  _Pragma("unroll") for (int m4_ = 0; m4_ < 4; ++m4_) \
  _Pragma("unroll") for (int n2_ = 0; n2_ < 2; ++n2_) { \
    int mi_ = (qm)*4 + m4_, ni_ = (qn)*2 + n2_; \
    acc[mi_][ni_] = __builtin_amdgcn_mfma_f32_16x16x32_bf16(aR[m4_][0], bR[ni_][0], acc[mi_][ni_], 0, 0, 0); \
    acc[mi_][ni_] = __builtin_amdgcn_mfma_f32_16x16x32_bf16(aR[m4_][1], bR[ni_][1], acc[mi_][ni_], 0, 0, 0); \
  } } while (0)

#define STG(Mat, ld, r0, rmax, t, ldsb) do { \
  int ks_ = (t) * 64; if (ks_ > Km64) ks_ = Km64; \
  int ra_ = (r0) + row0;      ra_ = ra_ < (rmax) ? ra_ : (rmax) - 1; \
  int rb_ = (r0) + row0 + 64; rb_ = rb_ < (rmax) ? rb_ : (rmax) - 1; \
  char* d_ = (char*)(ldsb) + dstoff; \
  gload_lds16((Mat) + (size_t)ra_ * (ld) + ks_ + kel, d_); \
  gload_lds16((Mat) + (size_t)rb_ * (ld) + ks_ + kel, d_ + 8192); \
} while (0)

#define SA(b, ha, t) STG(A, lda, m0 + (ha)*128, M, t, &As[b][(ha)*128][0])
#define SB(b, hb, t) STG(B, ldb, n0 + (hb)*128, N, t, &Bs[b][(hb)*128][0])

#define PHASE_TOP() do { __builtin_amdgcn_s_barrier(); \
  asm volatile("s_waitcnt lgkmcnt(0)" ::: "memory"); \
  __builtin_amdgcn_s_setprio(1); } while (0)
#define PHASE_END() do { __builtin_amdgcn_s_setprio(0); \
  __builtin_amdgcn_s_barrier(); } while (0)
#define PHASE_END_VM() do { __builtin_amdgcn_s_setprio(0); \
  asm volatile("s_waitcnt vmcnt(6)" ::: "memory"); \
  __builtin_amdgcn_s_barrier(); } while (0)

__global__ __launch_bounds__(512, 2) void gemm256(
    const u16* __restrict__ A, const u16* __restrict__ B, u16* __restrict__ C,
    int M, int N, int K, int lda, int ldb, int ldc)
{
    __shared__ __align__(16) u16 As[2][256][64];
    __shared__ __align__(16) u16 Bs[2][256][64];

    const int nmt = (M + 255) >> 8;
    const int ntn = (N + 255) >> 8;
    const int nwg = nmt * ntn;

    int bid = blockIdx.x;
    int q8 = nwg >> 3, r8 = nwg & 7;
    int xcd = bid & 7, lid = bid >> 3;
    int wgid = (xcd < r8 ? xcd * (q8 + 1) : r8 * (q8 + 1) + (xcd - r8) * q8) + lid;
    int per = ntn << 3;
    int g = wgid / per;
    int first = g << 3;
    int gsz = nmt - first; gsz = gsz < 8 ? gsz : 8;
    int rem = wgid - g * per;
    int mt = first + rem % gsz;
    int nt = rem / gsz;

    const int m0 = mt << 8, n0 = nt << 8;
    const int tid = threadIdx.x;
    const int wid = tid >> 6, ln = tid & 63;
    const int wr = wid >> 2, wc = wid & 3;
    const int lrow = ln & 15, khi = ln >> 4;
    const int wr16 = wr << 4, wc16 = wc << 4;
    const int cb0 = (khi << 4) ^ ((lrow & 7) << 4);
    const int cb1 = cb0 ^ 64;
    const int row0 = tid >> 3;
    const int kel = ((tid & 7) ^ (row0 & 7)) << 3;
    const int dstoff = (tid & 448) << 4;
    const int Km64 = K - 64;

    f32x4 acc[8][4];
#pragma unroll
    for (int m = 0; m < 8; ++m)
#pragma unroll
        for (int n = 0; n < 4; ++n)
#pragma unroll
            for (int j = 0; j < 4; ++j) acc[m][n][j] = 0.f;
    bf16x8 aR[4][2], bR[4][2];

    SA(0, 0, 0); SB(0, 0, 0); SB(0, 1, 0); SA(0, 1, 0);
    SA(1, 0, 1); SB(1, 0, 1); SB(1, 1, 1);
    asm volatile("s_waitcnt vmcnt(6)" ::: "memory");
    __builtin_amdgcn_s_barrier();

    const int nit = K >> 7;
    for (int it = 0; it < nit; ++it) {
        const int t1 = 2 * it + 1, t2 = 2 * it + 2, t3 = 2 * it + 3;
        DS_A(&As[0][0][0], 0); DS_B(&Bs[0][0][0], 0);
        SA(1, 1, t1);
        PHASE_TOP(); MM(0, 0); PHASE_END();
        DS_B(&Bs[0][0][0], 1);
        SA(0, 0, t2);
        PHASE_TOP(); MM(0, 1); PHASE_END();
        DS_A(&As[0][0][0], 1);
        SB(0, 0, t2);
        PHASE_TOP(); MM(1, 1); PHASE_END();
        SB(0, 1, t2);
        __builtin_amdgcn_s_barrier();
        __builtin_amdgcn_s_setprio(1);
        MM(1, 0);
        PHASE_END_VM();
        DS_A(&As[1][0][0], 0); DS_B(&Bs[1][0][0], 0);
        SA(0, 1, t2);
        PHASE_TOP(); MM(0, 0); PHASE_END();
        DS_B(&Bs[1][0][0], 1);
        SA(1, 0, t3);
        PHASE_TOP(); MM(0, 1); PHASE_END();
        DS_A(&As[1][0][0], 1);
        SB(1, 0, t3);
        PHASE_TOP(); MM(1, 1); PHASE_END();
        SB(1, 1, t3);
        __builtin_amdgcn_s_barrier();
        __builtin_amdgcn_s_setprio(1);
        MM(1, 0);
        PHASE_END_VM();
    }

#pragma unroll
    for (int m = 0; m < 8; ++m) {
        int gr0 = m0 + m * 32 + wr16 + (khi << 2);
#pragma unroll
        for (int n = 0; n < 4; ++n) {
            int gc = n0 + n * 64 + wc16 + lrow;
            if (gc >= N) continue;
#pragma unroll
            for (int j = 0; j < 4; ++j) {
                int gr = gr0 + j;
                if (gr >= M) continue;
                C[(size_t)gr * ldc + gc] = f2bf(acc[m][n][j]);
            }
        }
    }
}

// ================== 128x128 GEMM (small layers) ==================
template <int EPI>
__global__ __launch_bounds__(256, 2) void gemm_bt(
    const u16* __restrict__ A, const u16* __restrict__ B, u16* __restrict__ C,
    const float* __restrict__ bias, int M, int N, int K, int lda, int ldb, int ldc)
{
    __shared__ __align__(16) u16 As[128][64];
    __shared__ __align__(16) u16 Bs[128][64];

    const int nmt = (M + 127) >> 7;
    const int ntn = (N + 127) >> 7;
    int bid = blockIdx.x;
    int per_grp = 16 * ntn;
    int g = bid / per_grp;
    int first = g * 16;
    int gsz = min(16, nmt - first);
    int rem = bid - g * per_grp;
    int mt = first + rem % gsz;
    int nt = rem / gsz;

    const int m0 = mt << 7, n0 = nt << 7;
    const int tid = threadIdx.x;
    const int wv = tid >> 6, ln = tid & 63;
    const int wr = wv >> 1, wc = wv & 1;

    f32x4 acc[4][4];
#pragma unroll
    for (int m = 0; m < 4; ++m)
#pragma unroll
        for (int n = 0; n < 4; ++n)
#pragma unroll
            for (int j = 0; j < 4; ++j) acc[m][n][j] = 0.f;

    const int lrow = ln & 15;
    const int koff = (ln >> 4) << 3;

    for (int k0 = 0; k0 < K; k0 += 64) {
#pragma unroll
        for (int r = 0; r < 4; ++r) {
            int c = r * 256 + wv * 64 + ln;
            int row = c >> 3;
            int kc = (c & 7) << 3;
            int ga = m0 + row; ga = ga < M ? ga : M - 1;
            gload_lds16(A + (size_t)ga * lda + (k0 + kc),
                        (char*)&As[0][0] + (size_t)(r * 256 + wv * 64) * 16);
            int gb = n0 + row; gb = gb < N ? gb : N - 1;
            gload_lds16(B + (size_t)gb * ldb + (k0 + kc),
                        (char*)&Bs[0][0] + (size_t)(r * 256 + wv * 64) * 16);
        }
        __syncthreads();
#pragma unroll
        for (int kk = 0; kk < 2; ++kk) {
            bf16x8 af[4], bfr[4];
            const int krd = (kk << 5) + koff;
#pragma unroll
            for (int m = 0; m < 4; ++m)
                af[m] = *(const bf16x8*)&As[(wr << 6) + (m << 4) + lrow][krd];
#pragma unroll
            for (int n = 0; n < 4; ++n)
                bfr[n] = *(const bf16x8*)&Bs[(wc << 6) + (n << 4) + lrow][krd];
#pragma unroll
            for (int m = 0; m < 4; ++m)
#pragma unroll
                for (int n = 0; n < 4; ++n)
                    acc[m][n] = __builtin_amdgcn_mfma_f32_16x16x32_bf16(
                        af[m], bfr[n], acc[m][n], 0, 0, 0);
        }
        __syncthreads();
    }

    const int colb = ln & 15;
    const int rowb = (ln >> 4) << 2;
#pragma unroll
    for (int m = 0; m < 4; ++m) {
        int gr0 = m0 + (wr << 6) + (m << 4) + rowb;
#pragma unroll
        for (int n = 0; n < 4; ++n) {
            int gc = n0 + (wc << 6) + (n << 4) + colb;
            if (gc >= N) continue;
            float bv = (EPI == 1) ? bias[gc] : 0.f;
#pragma unroll
            for (int j = 0; j < 4; ++j) {
                int gr = gr0 + j;
                if (gr >= M) continue;
                float v = acc[m][n][j];
                if (EPI == 1) { v += bv; v = v > 0.f ? v : 0.f; }
                C[(size_t)gr * ldc + gc] = f2bf(v);
            }
        }
    }
}

// ---------------- fp32 -> bf16 convert (grid-stride)
__global__ void cvt_bf16(const float* __restrict__ in, u16* __restrict__ out, int n4)
{
    for (int i = blockIdx.x * 256 + threadIdx.x; i < n4; i += gridDim.x * 256) {
        float4 v = ((const float4*)in)[i];
        ushort4 o;
        o.x = f2bf(v.x); o.y = f2bf(v.y); o.z = f2bf(v.z); o.w = f2bf(v.w);
        ((ushort4*)out)[i] = o;
    }
}

// ---------------- weight transpose+convert: out[n][k](bf16,ld=Kpad) = src[k][n](f32)
__global__ void wtrans(const float* __restrict__ s0, const float* __restrict__ s1,
                       u16* __restrict__ out, int Kin, int Kpad, int N, int nsplit)
{
    __shared__ float t[32][33];
    int k0 = blockIdx.x << 5, n0 = blockIdx.y << 5;
    int tx = threadIdx.x, ty = threadIdx.y;
#pragma unroll
    for (int i = 0; i < 4; ++i) {
        int k = k0 + ty + (i << 3);
        int n = n0 + tx;
        float v = 0.f;
        if (k < Kin && n < N)
            v = (n < nsplit) ? s0[(size_t)k * nsplit + n]
                             : s1[(size_t)k * (N - nsplit) + (n - nsplit)];
        t[ty + (i << 3)][tx] = v;
    }
    __syncthreads();
#pragma unroll
    for (int i = 0; i < 4; ++i) {
        int n = n0 + ty + (i << 3);
        int k = k0 + tx;
        if (n < N && k < Kpad)
            out[(size_t)n * Kpad + k] = f2bf(t[tx][ty + (i << 3)]);
    }
}

// ================== CSR build (gather aggregation support) ==================
__global__ void deg_k(const int* __restrict__ dst, int* __restrict__ deg, int ne)
{
    int e = blockIdx.x * 256 + threadIdx.x;
    if (e < ne) atomicAdd(&deg[dst[e]], 1);
}

// single block, 256 threads; 79 contiguous nodes per thread
__global__ __launch_bounds__(256) void scan_k(const int* __restrict__ deg,
                                              int* __restrict__ off, int* __restrict__ cur)
{
    __shared__ int part[256];
    int t = threadIdx.x;
    int st = t * 79;
    int s = 0;
    for (int j = 0; j < 79; ++j) {
        int idx = st + j;
        if (idx < NN) s += deg[idx];
    }
    part[t] = s;
    __syncthreads();
    for (int d = 1; d < 256; d <<= 1) {
        int v = (t >= d) ? part[t - d] : 0;
        __syncthreads();
        part[t] += v;
        __syncthreads();
    }
    int run = part[t] - s;   // exclusive prefix
    for (int j = 0; j < 79; ++j) {
        int idx = st + j;
        if (idx < NN) {
            off[idx] = run;
            cur[idx] = run;
            run += deg[idx];
        }
    }
    if (t == 255) off[NN] = NE;
}

__global__ void fill_k(const int* __restrict__ src, const int* __restrict__ dst,
                       int* __restrict__ cur, int* __restrict__ esrc, int ne)
{
    int e = blockIdx.x * 256 + threadIdx.x;
    if (e < ne) {
        int p = atomicAdd(&cur[dst[e]], 1);
        esrc[p] = src[e];
    }
}

// ================== fused gather-mean + epilogue, layer 1 ==================
// h[b][c] = BN(relu(mean_j y1l[src_j][c] + b1[c] + y1r[b][c])), ld 1792, zero-pad
__device__ __forceinline__ void bn_emit(
    int b, int c, float sx, float sy, float sz, float sw, float inv,
    const u16* __restrict__ y1, const float* __restrict__ b1,
    const float* __restrict__ gam, const float* __restrict__ bet,
    const float* __restrict__ mn, const float* __restrict__ vr, u16* __restrict__ h)
{
    int col = c << 2;
    ushort4 yr = *(const ushort4*)&y1[(size_t)b * 3360 + 1680 + col];
    float4 bb = *(const float4*)&b1[col];
    float4 g4 = *(const float4*)&gam[col];
    float4 be = *(const float4*)&bet[col];
    float4 m4 = *(const float4*)&mn[col];
    float4 v4 = *(const float4*)&vr[col];
    float t0 = fmaxf(sx * inv + bb.x + bf2f(yr.x), 0.f);
    float t1 = fmaxf(sy * inv + bb.y + bf2f(yr.y), 0.f);
    float t2 = fmaxf(sz * inv + bb.z + bf2f(yr.z), 0.f);
    float t3 = fmaxf(sw * inv + bb.w + bf2f(yr.w), 0.f);
    t0 = (t0 - m4.x) * rsqrtf(v4.x + BN_EPS) * g4.x + be.x;
    t1 = (t1 - m4.y) * rsqrtf(v4.y + BN_EPS) * g4.y + be.y;
    t2 = (t2 - m4.z) * rsqrtf(v4.z + BN_EPS) * g4.z + be.z;
    t3 = (t3 - m4.w) * rsqrtf(v4.w + BN_EPS) * g4.w + be.w;
    ushort4 o;
    o.x = f2bf(t0); o.y = f2bf(t1); o.z = f2bf(t2); o.w = f2bf(t3);
    *(ushort4*)&h[(size_t)b * 1792 + col] = o;
}

__global__ __launch_bounds__(256) void agg_bn_k(
    const u16* __restrict__ y1, const int* __restrict__ off, const int* __restrict__ esrc,
    const float* __restrict__ b1, const float* __restrict__ gam, const float* __restrict__ bet,
    const float* __restrict__ mn, const float* __restrict__ vr, u16* __restrict__ h)
{
    int b = blockIdx.x, t = threadIdx.x;
    int o0 = off[b], o1 = off[b + 1];
    int deg = o1 - o0;
    const int c0 = t, c1 = t + 256;   // ushort4 chunks; 420 data chunks, 448 total (pad)
    float s0x = 0.f, s0y = 0.f, s0z = 0.f, s0w = 0.f;
    float s1x = 0.f, s1y = 0.f, s1z = 0.f, s1w = 0.f;
    for (int j = o0; j < o1; ++j) {
        int s = esrc[j];
        const u16* row = y1 + (size_t)s * 3360;
        ushort4 v = *(const ushort4*)&row[c0 << 2];
        s0x += bf2f(v.x); s0y += bf2f(v.y); s0z += bf2f(v.z); s0w += bf2f(v.w);
        if (t < 164) {
            ushort4 w = *(const ushort4*)&row[c1 << 2];
            s1x += bf2f(w.x); s1y += bf2f(w.y); s1z += bf2f(w.z); s1w += bf2f(w.w);
        }
    }
    float inv = 1.f / (deg > 1 ? (float)deg : 1.f);
    bn_emit(b, c0, s0x, s0y, s0z, s0w, inv, y1, b1, gam, bet, mn, vr, h);
    if (t < 164) {
        bn_emit(b, c1, s1x, s1y, s1z, s1w, inv, y1, b1, gam, bet, mn, vr, h);
    } else if (t < 192) {
        ushort4 z; z.x = 0; z.y = 0; z.z = 0; z.w = 0;
        *(ushort4*)&h[(size_t)b * 1792 + (c1 << 2)] = z;   // pad chunks 420..447
    }
}

// ================== fused gather-mean + epilogue, layer 2 ==================
// h2[b][c] = relu(mean_j y2l[src_j][c] + b2[c] + y2r[b][c]), 640 cols
__global__ __launch_bounds__(192) void agg_h2_k(
    const u16* __restrict__ y2, const int* __restrict__ off, const int* __restrict__ esrc,
    const float* __restrict__ b2, u16* __restrict__ h2)
{
    int b = blockIdx.x, t = threadIdx.x;
    if (t >= 160) return;
    int o0 = off[b], o1 = off[b + 1];
    int deg = o1 - o0;
    float sx = 0.f, sy = 0.f, sz = 0.f, sw = 0.f;
    for (int j = o0; j < o1; ++j) {
        int s = esrc[j];
        ushort4 v = *(const ushort4*)&y2[(size_t)s * 1280 + (t << 2)];
        sx += bf2f(v.x); sy += bf2f(v.y); sz += bf2f(v.z); sw += bf2f(v.w);
    }
    float inv = 1.f / (deg > 1 ? (float)deg : 1.f);
    int col = t << 2;
    ushort4 yr = *(const ushort4*)&y2[(size_t)b * 1280 + 640 + col];
    float4 bb = *(const float4*)&b2[col];
    ushort4 o;
    o.x = f2bf(fmaxf(sx * inv + bb.x + bf2f(yr.x), 0.f));
    o.y = f2bf(fmaxf(sy * inv + bb.y + bf2f(yr.y), 0.f));
    o.z = f2bf(fmaxf(sz * inv + bb.z + bf2f(yr.z), 0.f));
    o.w = f2bf(fmaxf(sw * inv + bb.w + bf2f(yr.w), 0.f));
    *(ushort4*)&h2[(size_t)b * 640 + col] = o;
}

// ---------------- final lin3
__global__ void lin3_k(const u16* __restrict__ o2, const float* __restrict__ W,
                       const float* __restrict__ b, float* __restrict__ out)
{
    __shared__ float ws[320];
    for (int j = threadIdx.x; j < 320; j += 256) ws[j] = W[j];
    __syncthreads();
    int i = blockIdx.x * 256 + threadIdx.x;
    if (i >= NN) return;
    float a0 = b[0], a1 = b[1];
    const u16* row = o2 + (size_t)i * 160;
#pragma unroll
    for (int k8 = 0; k8 < 20; ++k8) {
        ushort4 v0 = *(const ushort4*)&row[k8 * 8];
        ushort4 v1 = *(const ushort4*)&row[k8 * 8 + 4];
        int kb = k8 * 8;
        float f;
        f = bf2f(v0.x); a0 += f * ws[(kb + 0) * 2]; a1 += f * ws[(kb + 0) * 2 + 1];
        f = bf2f(v0.y); a0 += f * ws[(kb + 1) * 2]; a1 += f * ws[(kb + 1) * 2 + 1];
        f = bf2f(v0.z); a0 += f * ws[(kb + 2) * 2]; a1 += f * ws[(kb + 2) * 2 + 1];
        f = bf2f(v0.w); a0 += f * ws[(kb + 3) * 2]; a1 += f * ws[(kb + 3) * 2 + 1];
        f = bf2f(v1.x); a0 += f * ws[(kb + 4) * 2]; a1 += f * ws[(kb + 4) * 2 + 1];
        f = bf2f(v1.y); a0 += f * ws[(kb + 5) * 2]; a1 += f * ws[(kb + 5) * 2 + 1];
        f = bf2f(v1.z); a0 += f * ws[(kb + 6) * 2]; a1 += f * ws[(kb + 6) * 2 + 1];
        f = bf2f(v1.w); a0 += f * ws[(kb + 7) * 2]; a1 += f * ws[(kb + 7) * 2 + 1];
    }
    out[(size_t)i * 2 + 0] = a0;
    out[(size_t)i * 2 + 1] = a1;
}

extern "C" void kernel_launch(void* const* d_in, const int* in_sizes, int n_in,
                              void* d_out, int out_size, void* d_ws, size_t ws_size,
                              hipStream_t stream)
{
    const float* x     = (const float*)d_in[0];
    const float* W1l   = (const float*)d_in[1];
    const float* b1    = (const float*)d_in[2];
    const float* W1r   = (const float*)d_in[3];
    const float* W2l   = (const float*)d_in[4];
    const float* b2    = (const float*)d_in[5];
    const float* W2r   = (const float*)d_in[6];
    const float* gam   = (const float*)d_in[7];
    const float* bet   = (const float*)d_in[8];
    const float* bmean = (const float*)d_in[9];
    const float* bvar  = (const float*)d_in[10];
    const float* l1W   = (const float*)d_in[11];
    const float* l1b   = (const float*)d_in[12];
    const float* l2W   = (const float*)d_in[13];
    const float* l2b   = (const float*)d_in[14];
    const float* l3W   = (const float*)d_in[15];
    const float* l3b   = (const float*)d_in[16];
    const int*   ei    = (const int*)d_in[17];
    const int* src = ei, * dst = ei + NE;

    char* ws = (char*)d_ws;
    // liveness-overlaid workspace layout
    u16*   y1   = (u16*)(ws + 0);            // [NN][3360] bf16 (GEMM1 out; dead after agg_bn)
    u16*   y2   = (u16*)(ws + 0);            // [NN][1280] bf16 (GEMM2 out; dead after agg_h2)
    u16*   o1   = (u16*)(ws + 0);            // [NN][320]  bf16
    u16*   o2   = (u16*)(ws + 16000000);     // [NN][160]  bf16
    u16*   xbf  = (u16*)(ws + 136000000);    // [NN][5120] bf16 (dead after GEMM1)
    u16*   hbuf = (u16*)(ws + 136000000);    // [NN][1792] bf16 (dead after GEMM2)
    u16*   h2   = (u16*)(ws + 136000000);    // [NN][640]  bf16
    u16*   w1T  = (u16*)(ws + 341000000);    // [3360][5120] bf16 (dead after GEMM1)
    u16*   w2T  = (u16*)(ws + 341000000);    // [1280][1792] bf16
    u16*   l1T  = (u16*)(ws + 346000000);    // [320][640] bf16
    u16*   l2T  = (u16*)(ws + 347000000);    // [160][320] bf16
    // CSR in dead-w1T region (built after GEMM1)
    int*   deg  = (int*)(ws + 350000000);    // [NN]
    int*   off  = (int*)(ws + 350100000);    // [NN+1]
    int*   cur  = (int*)(ws + 350200000);    // [NN]
    int*   esrc = (int*)(ws + 350300000);    // [NE]

    // 1) x -> bf16 ; W1 -> [3360][5120] bf16 (transposed, concat [W1l|W1r])
    cvt_bf16<<<2048, 256, 0, stream>>>(x, xbf, NN * 5120 / 4);
    wtrans<<<dim3(160, 105), dim3(32, 8), 0, stream>>>(W1l, W1r, w1T, 5120, 5120, 3360, 1680);

    // 2) GEMM1 (8-phase 256^2): y1[NN][3360] = xbf @ w1T^T
    gemm256<<<79 * 14, 512, 0, stream>>>(xbf, w1T, y1, NN, 3360, 5120, 5120, 5120, 3360);

    // 3) CSR build (w1T dead now)
    hipMemsetAsync(deg, 0, NN * sizeof(int), stream);
    deg_k<<<(NE + 255) / 256, 256, 0, stream>>>(dst, deg, NE);
    scan_k<<<1, 256, 0, stream>>>(deg, off, cur);
    fill_k<<<(NE + 255) / 256, 256, 0, stream>>>(src, dst, cur, esrc, NE);

    // 4) fused gather-mean + b1 + self + relu + BN -> hbuf (K-padded 1792)
    agg_bn_k<<<NN, 256, 0, stream>>>(y1, off, esrc, b1, gam, bet, bmean, bvar, hbuf);

    // 5) W2 -> [1280][1792] bf16 (zero-padded K)
    wtrans<<<dim3(56, 40), dim3(32, 8), 0, stream>>>(W2l, W2r, w2T, 1680, 1792, 1280, 640);

    // 6) GEMM2 (8-phase 256^2): y2[NN][1280] = hbuf @ w2T^T
    gemm256<<<79 * 5, 512, 0, stream>>>(hbuf, w2T, y2, NN, 1280, 1792, 1792, 1792, 1280);

    // 7) fused gather-mean + b2 + self + relu -> h2
    agg_h2_k<<<NN, 192, 0, stream>>>(y2, off, esrc, b2, h2);

    // 8) lin1/lin2 weights transposed
    wtrans<<<dim3(20, 10), dim3(32, 8), 0, stream>>>(l1W, l1W, l1T, 640, 640, 320, 320);
    wtrans<<<dim3(10, 5), dim3(32, 8), 0, stream>>>(l2W, l2W, l2T, 320, 320, 160, 160);

    // 9) GEMM3: o1 = relu(h2 @ l1T^T + l1b)   [NN][320]
    gemm_bt<1><<<157 * 3, 256, 0, stream>>>(h2, l1T, o1, l1b,
                                            NN, 320, 640, 640, 640, 320);

    // 10) GEMM4: o2 = relu(o1 @ l2T^T + l2b)  [NN][160]
    gemm_bt<1><<<157 * 2, 256, 0, stream>>>(o1, l2T, o2, l2b,
                                            NN, 160, 320, 320, 320, 160);

    // 11) lin3 -> out [NN][2] fp32
    lin3_k<<<(NN + 255) / 256, 256, 0, stream>>>(o2, l3W, l3b, (float*)d_out);
}